// Round 1
// baseline (805.489 us; speedup 1.0000x reference)
//
#include <hip/hip_runtime.h>
#include <hip/hip_bf16.h>
#include <math.h>

#define HEADS 4

// ---------------- CSR build ----------------

__global__ void init_deg_k(int* deg, int N) {
    int i = blockIdx.x * blockDim.x + threadIdx.x;
    if (i < N) deg[i] = 1;  // self loop
}

__global__ void count_deg_k(const int* __restrict__ dst, int* __restrict__ deg, int E) {
    int i = blockIdx.x * blockDim.x + threadIdx.x;
    if (i < E) atomicAdd(&deg[dst[i]], 1);
}

__global__ void scan_deg_k(const int* __restrict__ deg, int* __restrict__ ofs,
                           int* __restrict__ cursor, int N) {
    __shared__ int s[1024];
    int t = threadIdx.x;
    int chunk = (N + 1023) / 1024;
    int b = t * chunk;
    int e = min(b + chunk, N);
    int sum = 0;
    for (int i = b; i < e; i++) sum += deg[i];
    s[t] = sum;
    __syncthreads();
    for (int off = 1; off < 1024; off <<= 1) {
        int v = 0;
        if (t >= off) v = s[t - off];
        __syncthreads();
        s[t] += v;
        __syncthreads();
    }
    int run = (t == 0) ? 0 : s[t - 1];
    for (int i = b; i < e; i++) {
        ofs[i] = run; cursor[i] = run;
        run += deg[i];
    }
    if (t == 1023) ofs[N] = s[1023];
}

__global__ void scatter_k(const int* __restrict__ src, const int* __restrict__ dst,
                          int* __restrict__ cursor, int* __restrict__ csr, int E, int N) {
    int i = blockIdx.x * blockDim.x + threadIdx.x;
    if (i < E) {
        int d = dst[i];
        int p = atomicAdd(&cursor[d], 1);
        csr[p] = src[i];
    } else if (i < E + N) {
        int n = i - E;
        int p = atomicAdd(&cursor[n], 1);
        csr[p] = n;
    }
}

// ---------------- fp32 tiled GEMM: C = A[M,K] @ B[K,Nn] ----------------
// BM=BN=64, BK=32, block (16,16), 4x4 per thread. Nn % 64 == 0, K % 32 == 0.

__global__ __launch_bounds__(256) void sgemm_k(const float* __restrict__ A,
                                               const float* __restrict__ B,
                                               float* __restrict__ C_,
                                               int M, int Nn, int K) {
    constexpr int BM = 64, BN = 64, BK = 32;
    __shared__ float As[BK][BM + 4];
    __shared__ float Bs[BK][BN];
    int tx = threadIdx.x, ty = threadIdx.y;
    int tid = ty * 16 + tx;
    int row0 = blockIdx.y * BM;
    int col0 = blockIdx.x * BN;
    float acc[4][4] = {};
    for (int k0 = 0; k0 < K; k0 += BK) {
        constexpr int AF4 = BM * BK / 4;  // 512
        #pragma unroll
        for (int f = tid; f < AF4; f += 256) {
            int r = f / (BK / 4);
            int c4 = f % (BK / 4);
            int gr = row0 + r;
            float4 v = make_float4(0.f, 0.f, 0.f, 0.f);
            if (gr < M) v = *(const float4*)(A + (size_t)gr * K + k0 + c4 * 4);
            As[c4 * 4 + 0][r] = v.x;
            As[c4 * 4 + 1][r] = v.y;
            As[c4 * 4 + 2][r] = v.z;
            As[c4 * 4 + 3][r] = v.w;
        }
        constexpr int BF4 = BK * BN / 4;  // 512
        #pragma unroll
        for (int f = tid; f < BF4; f += 256) {
            int r = f / (BN / 4);
            int c4 = f % (BN / 4);
            *(float4*)(&Bs[r][c4 * 4]) = *(const float4*)(B + (size_t)(k0 + r) * Nn + col0 + c4 * 4);
        }
        __syncthreads();
        #pragma unroll
        for (int k = 0; k < BK; k++) {
            float a4[4], b4[4];
            *(float4*)a4 = *(const float4*)&As[k][ty * 4];
            *(float4*)b4 = *(const float4*)&Bs[k][tx * 4];
            #pragma unroll
            for (int i = 0; i < 4; i++)
                #pragma unroll
                for (int j = 0; j < 4; j++)
                    acc[i][j] = fmaf(a4[i], b4[j], acc[i][j]);
        }
        __syncthreads();
    }
    #pragma unroll
    for (int i = 0; i < 4; i++) {
        int gr = row0 + ty * 4 + i;
        if (gr < M) {
            *(float4*)(C_ + (size_t)gr * Nn + col0 + tx * 4) =
                make_float4(acc[i][0], acc[i][1], acc[i][2], acc[i][3]);
        }
    }
}

// ---------------- alpha dots: alpha_s[n,h] = <h[n,h,:], a_src[h,:]> ----------------

template <int C>
__global__ void alphas_k(const float* __restrict__ hmat, const float* __restrict__ avs,
                         const float* __restrict__ avd, float* __restrict__ os,
                         float* __restrict__ od, int N) {
    int idx = blockIdx.x * blockDim.x + threadIdx.x;
    if (idx >= N * HEADS) return;
    int n = idx >> 2, h = idx & 3;
    const float4* hp = (const float4*)(hmat + (size_t)n * HEADS * C + h * C);
    const float4* sp = (const float4*)(avs + h * C);
    const float4* dp = (const float4*)(avd + h * C);
    float ss = 0.f, sd = 0.f;
    #pragma unroll
    for (int k = 0; k < C / 4; k++) {
        float4 hv = hp[k], sv = sp[k], dv = dp[k];
        ss += hv.x * sv.x + hv.y * sv.y + hv.z * sv.z + hv.w * sv.w;
        sd += hv.x * dv.x + hv.y * dv.y + hv.z * dv.z + hv.w * dv.w;
    }
    os[idx] = ss;
    od[idx] = sd;
}

// ---------------- GAT aggregation (block per dst node, online softmax) ----------------
// block = HEADS*C threads; thread t owns output (head t/C, chan t%C).

template <int C>
__global__ __launch_bounds__(HEADS * C) void gat_agg_k(
    const float* __restrict__ hsrc,   // [N, HEADS*C]
    const float* __restrict__ as,     // [N, HEADS]
    const float* __restrict__ ad,     // [N, HEADS]
    const int* __restrict__ ofs,      // [N+1]
    const int* __restrict__ csr,
    const float* __restrict__ bias,   // [HEADS*C]
    float* __restrict__ out, int N) {
    constexpr int CHUNK = 64;
    __shared__ float s_p[CHUNK * HEADS];
    __shared__ int s_src[CHUNK];
    __shared__ float s_m[HEADS], s_l[HEADS], s_scale[HEADS];
    int i = blockIdx.x;
    int t = threadIdx.x;
    int ht = t / C;
    int beg = ofs[i], end = ofs[i + 1];
    if (t < HEADS) { s_m[t] = -INFINITY; s_l[t] = 0.f; }
    __syncthreads();
    float accv = 0.f;
    for (int base = beg; base < end; base += CHUNK) {
        int cl = min(CHUNK, end - base);
        if (t < cl) {
            int s = csr[base + t];
            s_src[t] = s;
            float4 av = *(const float4*)(as + (size_t)s * HEADS);
            float4 dv = *(const float4*)(ad + (size_t)i * HEADS);
            float e0 = av.x + dv.x; e0 = (e0 > 0.f) ? e0 : 0.2f * e0;
            float e1 = av.y + dv.y; e1 = (e1 > 0.f) ? e1 : 0.2f * e1;
            float e2 = av.z + dv.z; e2 = (e2 > 0.f) ? e2 : 0.2f * e2;
            float e3 = av.w + dv.w; e3 = (e3 > 0.f) ? e3 : 0.2f * e3;
            s_p[t * HEADS + 0] = e0;
            s_p[t * HEADS + 1] = e1;
            s_p[t * HEADS + 2] = e2;
            s_p[t * HEADS + 3] = e3;
        }
        __syncthreads();
        if (t < HEADS) {
            float m_old = s_m[t];
            float cmax = -INFINITY;
            for (int j = 0; j < cl; j++) cmax = fmaxf(cmax, s_p[j * HEADS + t]);
            float m_new = fmaxf(m_old, cmax);
            float sc = __expf(m_old - m_new);  // 0 when m_old == -inf
            float sum = 0.f;
            for (int j = 0; j < cl; j++) {
                float p = __expf(s_p[j * HEADS + t] - m_new);
                s_p[j * HEADS + t] = p;
                sum += p;
            }
            s_l[t] = s_l[t] * sc + sum;
            s_m[t] = m_new;
            s_scale[t] = sc;
        }
        __syncthreads();
        accv *= s_scale[ht];
        for (int j = 0; j < cl; j++) {
            accv = fmaf(s_p[j * HEADS + ht], hsrc[(size_t)s_src[j] * (HEADS * C) + t], accv);
        }
        __syncthreads();
    }
    float r = accv / s_l[ht] + bias[t];
    out[(size_t)i * (HEADS * C) + t] = (r > 0.f) ? r : 0.f;
}

// ---------------- pooling + FC ----------------

__global__ void graph_bounds_k(const int* __restrict__ batch, int N, int* __restrict__ bstart) {
    int g = threadIdx.x;
    if (g <= 64) {
        int lo = 0, hi = N;
        while (lo < hi) {
            int mid = (lo + hi) >> 1;
            if (batch[mid] < g) lo = mid + 1; else hi = mid;
        }
        bstart[g] = lo;
    }
}

__global__ void pool_k(const float* __restrict__ g2, const int* __restrict__ bstart,
                       float* __restrict__ pooled) {
    int g = blockIdx.x, c = threadIdx.x;  // 64 threads
    int s = bstart[g], e = bstart[g + 1];
    float acc = 0.f;
    for (int n = s; n < e; n++) acc += g2[(size_t)n * 64 + c];
    float cnt = (float)max(e - s, 1);
    pooled[g * 64 + c] = acc / cnt;
}

__global__ void fc_k(const float* __restrict__ pooled, const float* __restrict__ w,
                     const float* __restrict__ b, float* __restrict__ out) {
    int g = blockIdx.x, o = threadIdx.x;  // 32 threads
    float acc = b[o];
    for (int k = 0; k < 64; k++) acc = fmaf(pooled[g * 64 + k], w[k * 32 + o], acc);
    out[g * 32 + o] = acc;
}

// ---------------- launch ----------------

static inline size_t align_up(size_t x, size_t a) { return (x + a - 1) & ~(a - 1); }

extern "C" void kernel_launch(void* const* d_in, const int* in_sizes, int n_in,
                              void* d_out, int out_size, void* d_ws, size_t ws_size,
                              hipStream_t stream) {
    const float* x      = (const float*)d_in[0];
    const int*   ei     = (const int*)d_in[1];
    const int*   batch  = (const int*)d_in[2];
    const float* W1     = (const float*)d_in[3];
    const float* a_src1 = (const float*)d_in[4];
    const float* a_dst1 = (const float*)d_in[5];
    const float* b1     = (const float*)d_in[6];
    const float* W2     = (const float*)d_in[7];
    const float* a_src2 = (const float*)d_in[8];
    const float* a_dst2 = (const float*)d_in[9];
    const float* b2     = (const float*)d_in[10];
    const float* fc_w   = (const float*)d_in[11];
    const float* fc_b   = (const float*)d_in[12];
    float* out = (float*)d_out;

    const int N = in_sizes[2];
    const int E = in_sizes[1] / 2;
    const int F_in = in_sizes[0] / N;   // 128
    const int D1 = HEADS * 64;          // 256
    const int D2 = HEADS * 16;          // 64

    const int* src = ei;
    const int* dst = ei + E;

    // workspace layout (h2/as2/ad2/g2 overlay h1, which dies after layer-1 agg)
    char* w = (char*)d_ws;
    size_t off = 0;
    auto alloc = [&](size_t bytes) {
        size_t p = off;
        off = align_up(off + bytes, 256);
        return (void*)(w + p);
    };
    int* deg    = (int*)alloc((size_t)N * 4);
    int* ofs    = (int*)alloc((size_t)(N + 1) * 4);
    int* cursor = (int*)alloc((size_t)N * 4);
    int* csr    = (int*)alloc((size_t)(E + N) * 4);
    int* bstart = (int*)alloc(65 * 4);
    float* pooled = (float*)alloc(64 * 64 * 4);
    float* as1  = (float*)alloc((size_t)N * HEADS * 4);
    float* ad1  = (float*)alloc((size_t)N * HEADS * 4);
    float* g1   = (float*)alloc((size_t)N * D1 * 4);
    // h1 region; after layer-1 agg reused for h2/as2/ad2/g2
    char* h1base = (char*)alloc((size_t)N * D1 * 4);
    float* h1 = (float*)h1base;
    float* h2  = (float*)h1base;                                   // [N, 64]
    float* as2 = (float*)(h1base + align_up((size_t)N * D2 * 4, 256));
    float* ad2 = (float*)((char*)as2 + align_up((size_t)N * HEADS * 4, 256));
    float* g2  = (float*)((char*)ad2 + align_up((size_t)N * HEADS * 4, 256));

    // --- CSR build ---
    init_deg_k<<<(N + 255) / 256, 256, 0, stream>>>(deg, N);
    count_deg_k<<<(E + 255) / 256, 256, 0, stream>>>(dst, deg, E);
    scan_deg_k<<<1, 1024, 0, stream>>>(deg, ofs, cursor, N);
    scatter_k<<<(E + N + 255) / 256, 256, 0, stream>>>(src, dst, cursor, csr, E, N);

    // --- layer 1 ---
    {
        dim3 grid(D1 / 64, (N + 63) / 64);
        sgemm_k<<<grid, dim3(16, 16), 0, stream>>>(x, W1, h1, N, D1, F_in);
    }
    alphas_k<64><<<(N * HEADS + 255) / 256, 256, 0, stream>>>(h1, a_src1, a_dst1, as1, ad1, N);
    gat_agg_k<64><<<N, 256, 0, stream>>>(h1, as1, ad1, ofs, csr, b1, g1, N);

    // --- layer 2 ---
    {
        dim3 grid(D2 / 64, (N + 63) / 64);
        sgemm_k<<<grid, dim3(16, 16), 0, stream>>>(g1, W2, h2, N, D2, D1);
    }
    alphas_k<16><<<(N * HEADS + 255) / 256, 256, 0, stream>>>(h2, a_src2, a_dst2, as2, ad2, N);
    gat_agg_k<16><<<N, 64, 0, stream>>>(h2, as2, ad2, ofs, csr, b2, g2, N);

    // --- pool + fc ---
    graph_bounds_k<<<1, 128, 0, stream>>>(batch, N, bstart);
    pool_k<<<64, 64, 0, stream>>>(g2, bstart, pooled);
    fc_k<<<64, 32, 0, stream>>>(pooled, fc_w, fc_b, out);
}

// Round 2
// 612.341 us; speedup vs baseline: 1.3154x; 1.3154x over previous
//
#include <hip/hip_runtime.h>
#include <hip/hip_bf16.h>
#include <math.h>

#define HEADS 4

// ---------------- CSR build ----------------

__global__ void init_deg_k(int* deg, int N) {
    int i = blockIdx.x * blockDim.x + threadIdx.x;
    if (i < N) deg[i] = 1;  // self loop
}

__global__ void count_deg_k(const int* __restrict__ dst, int* __restrict__ deg, int E) {
    int i = blockIdx.x * blockDim.x + threadIdx.x;
    if (i < E) atomicAdd(&deg[dst[i]], 1);
}

__global__ void scan_deg_k(const int* __restrict__ deg, int* __restrict__ ofs,
                           int* __restrict__ cursor, int N) {
    __shared__ int s[1024];
    int t = threadIdx.x;
    int chunk = (N + 1023) / 1024;
    int b = t * chunk;
    int e = min(b + chunk, N);
    int sum = 0;
    for (int i = b; i < e; i++) sum += deg[i];
    s[t] = sum;
    __syncthreads();
    for (int off = 1; off < 1024; off <<= 1) {
        int v = 0;
        if (t >= off) v = s[t - off];
        __syncthreads();
        s[t] += v;
        __syncthreads();
    }
    int run = (t == 0) ? 0 : s[t - 1];
    for (int i = b; i < e; i++) {
        ofs[i] = run; cursor[i] = run;
        run += deg[i];
    }
    if (t == 1023) ofs[N] = s[1023];
}

__global__ void scatter_k(const int* __restrict__ src, const int* __restrict__ dst,
                          int* __restrict__ cursor, int* __restrict__ csr, int E, int N) {
    int i = blockIdx.x * blockDim.x + threadIdx.x;
    if (i < E) {
        int d = dst[i];
        int p = atomicAdd(&cursor[d], 1);
        csr[p] = src[i];
    } else if (i < E + N) {
        int n = i - E;
        int p = atomicAdd(&cursor[n], 1);
        csr[p] = n;
    }
}

// ---------------- fp32 tiled GEMM: C = A[M,K] @ B[K,Nn] ----------------
// BM=BN=64, BK=32, block (16,16), 4x4 per thread. Nn % 64 == 0, K % 32 == 0.

__global__ __launch_bounds__(256) void sgemm_k(const float* __restrict__ A,
                                               const float* __restrict__ B,
                                               float* __restrict__ C_,
                                               int M, int Nn, int K) {
    constexpr int BM = 64, BN = 64, BK = 32;
    __shared__ float As[BK][BM + 4];
    __shared__ float Bs[BK][BN];
    int tx = threadIdx.x, ty = threadIdx.y;
    int tid = ty * 16 + tx;
    int row0 = blockIdx.y * BM;
    int col0 = blockIdx.x * BN;
    float acc[4][4] = {};
    for (int k0 = 0; k0 < K; k0 += BK) {
        constexpr int AF4 = BM * BK / 4;  // 512
        #pragma unroll
        for (int f = tid; f < AF4; f += 256) {
            int r = f / (BK / 4);
            int c4 = f % (BK / 4);
            int gr = row0 + r;
            float4 v = make_float4(0.f, 0.f, 0.f, 0.f);
            if (gr < M) v = *(const float4*)(A + (size_t)gr * K + k0 + c4 * 4);
            As[c4 * 4 + 0][r] = v.x;
            As[c4 * 4 + 1][r] = v.y;
            As[c4 * 4 + 2][r] = v.z;
            As[c4 * 4 + 3][r] = v.w;
        }
        constexpr int BF4 = BK * BN / 4;  // 512
        #pragma unroll
        for (int f = tid; f < BF4; f += 256) {
            int r = f / (BN / 4);
            int c4 = f % (BN / 4);
            *(float4*)(&Bs[r][c4 * 4]) = *(const float4*)(B + (size_t)(k0 + r) * Nn + col0 + c4 * 4);
        }
        __syncthreads();
        #pragma unroll
        for (int k = 0; k < BK; k++) {
            float a4[4], b4[4];
            *(float4*)a4 = *(const float4*)&As[k][ty * 4];
            *(float4*)b4 = *(const float4*)&Bs[k][tx * 4];
            #pragma unroll
            for (int i = 0; i < 4; i++)
                #pragma unroll
                for (int j = 0; j < 4; j++)
                    acc[i][j] = fmaf(a4[i], b4[j], acc[i][j]);
        }
        __syncthreads();
    }
    #pragma unroll
    for (int i = 0; i < 4; i++) {
        int gr = row0 + ty * 4 + i;
        if (gr < M) {
            *(float4*)(C_ + (size_t)gr * Nn + col0 + tx * 4) =
                make_float4(acc[i][0], acc[i][1], acc[i][2], acc[i][3]);
        }
    }
}

// ---------------- alpha dots: alpha_s[n,h] = <h[n,h,:], a_src[h,:]> ----------------

template <int C>
__global__ void alphas_k(const float* __restrict__ hmat, const float* __restrict__ avs,
                         const float* __restrict__ avd, float* __restrict__ os,
                         float* __restrict__ od, int N) {
    int idx = blockIdx.x * blockDim.x + threadIdx.x;
    if (idx >= N * HEADS) return;
    int n = idx >> 2, h = idx & 3;
    const float4* hp = (const float4*)(hmat + (size_t)n * HEADS * C + h * C);
    const float4* sp = (const float4*)(avs + h * C);
    const float4* dp = (const float4*)(avd + h * C);
    float ss = 0.f, sd = 0.f;
    #pragma unroll
    for (int k = 0; k < C / 4; k++) {
        float4 hv = hp[k], sv = sp[k], dv = dp[k];
        ss += hv.x * sv.x + hv.y * sv.y + hv.z * sv.z + hv.w * sv.w;
        sd += hv.x * dv.x + hv.y * dv.y + hv.z * dv.z + hv.w * dv.w;
    }
    os[idx] = ss;
    od[idx] = sd;
}

// ---------------- GAT aggregation (block per dst node, online softmax) ----------------
// block = HEADS*C threads; thread t owns output (head t/C, chan t%C).

template <int C>
__global__ __launch_bounds__(HEADS * C) void gat_agg_k(
    const float* __restrict__ hsrc,   // [N, HEADS*C]
    const float* __restrict__ as,     // [N, HEADS]
    const float* __restrict__ ad,     // [N, HEADS]
    const int* __restrict__ ofs,      // [N+1]
    const int* __restrict__ csr,
    const float* __restrict__ bias,   // [HEADS*C]
    float* __restrict__ out, int N) {
    constexpr int CHUNK = 64;
    __shared__ float s_p[CHUNK * HEADS];
    __shared__ int s_src[CHUNK];
    __shared__ float s_m[HEADS], s_l[HEADS], s_scale[HEADS];
    int i = blockIdx.x;
    int t = threadIdx.x;
    int ht = t / C;
    int beg = ofs[i], end = ofs[i + 1];
    if (t < HEADS) { s_m[t] = -INFINITY; s_l[t] = 0.f; }
    __syncthreads();
    float accv = 0.f;
    for (int base = beg; base < end; base += CHUNK) {
        int cl = min(CHUNK, end - base);
        if (t < cl) {
            int s = csr[base + t];
            s_src[t] = s;
            float4 av = *(const float4*)(as + (size_t)s * HEADS);
            float4 dv = *(const float4*)(ad + (size_t)i * HEADS);
            float e0 = av.x + dv.x; e0 = (e0 > 0.f) ? e0 : 0.2f * e0;
            float e1 = av.y + dv.y; e1 = (e1 > 0.f) ? e1 : 0.2f * e1;
            float e2 = av.z + dv.z; e2 = (e2 > 0.f) ? e2 : 0.2f * e2;
            float e3 = av.w + dv.w; e3 = (e3 > 0.f) ? e3 : 0.2f * e3;
            s_p[t * HEADS + 0] = e0;
            s_p[t * HEADS + 1] = e1;
            s_p[t * HEADS + 2] = e2;
            s_p[t * HEADS + 3] = e3;
        }
        __syncthreads();
        if (t < HEADS) {
            float m_old = s_m[t];
            float cmax = -INFINITY;
            for (int j = 0; j < cl; j++) cmax = fmaxf(cmax, s_p[j * HEADS + t]);
            float m_new = fmaxf(m_old, cmax);
            float sc = __expf(m_old - m_new);  // 0 when m_old == -inf
            float sum = 0.f;
            for (int j = 0; j < cl; j++) {
                float p = __expf(s_p[j * HEADS + t] - m_new);
                s_p[j * HEADS + t] = p;
                sum += p;
            }
            s_l[t] = s_l[t] * sc + sum;
            s_m[t] = m_new;
            s_scale[t] = sc;
        }
        __syncthreads();
        accv *= s_scale[ht];
        for (int j = 0; j < cl; j++) {
            accv = fmaf(s_p[j * HEADS + ht], hsrc[(size_t)s_src[j] * (HEADS * C) + t], accv);
        }
        __syncthreads();
    }
    float r = accv / s_l[ht] + bias[t];
    out[(size_t)i * (HEADS * C) + t] = (r > 0.f) ? r : 0.f;
}

// ---------------- pooling + FC ----------------

__global__ void graph_bounds_k(const int* __restrict__ batch, int N, int* __restrict__ bstart) {
    int g = threadIdx.x;
    if (g <= 64) {
        int lo = 0, hi = N;
        while (lo < hi) {
            int mid = (lo + hi) >> 1;
            if (batch[mid] < g) lo = mid + 1; else hi = mid;
        }
        bstart[g] = lo;
    }
}

__global__ void pool_zero_k(float* __restrict__ sums) {
    sums[blockIdx.x * blockDim.x + threadIdx.x] = 0.f;
}

// node-parallel pooled sum: block covers 256 consecutive nodes; batch is sorted,
// so each thread flushes one atomicAdd per (graph run) it encounters (~1-2).
__global__ __launch_bounds__(256) void pool_sum_k(const float* __restrict__ g2,
                                                  const int* __restrict__ batch,
                                                  float* __restrict__ sums, int N) {
    int c = threadIdx.x & 63;   // channel; lanes of a wave cover one node row (coalesced)
    int r = threadIdx.x >> 6;   // node sub-lane 0..3
    int base = blockIdx.x * 256;
    int lim = min(base + 256, N);
    float acc = 0.f;
    int cur = -1;
    for (int n = base + r; n < lim; n += 4) {
        int g = batch[n];
        if (g != cur) {
            if (cur >= 0) atomicAdd(&sums[cur * 64 + c], acc);
            acc = 0.f;
            cur = g;
        }
        acc += g2[(size_t)n * 64 + c];
    }
    if (cur >= 0) atomicAdd(&sums[cur * 64 + c], acc);
}

__global__ void fc_k(const float* __restrict__ sums, const int* __restrict__ bstart,
                     const float* __restrict__ w, const float* __restrict__ b,
                     float* __restrict__ out) {
    int g = blockIdx.x, o = threadIdx.x;  // 32 threads
    float cnt = (float)max(bstart[g + 1] - bstart[g], 1);
    float inv = 1.f / cnt;
    float acc = b[o];
    for (int k = 0; k < 64; k++) acc = fmaf(sums[g * 64 + k] * inv, w[k * 32 + o], acc);
    out[g * 32 + o] = acc;
}

// ---------------- launch ----------------

static inline size_t align_up(size_t x, size_t a) { return (x + a - 1) & ~(a - 1); }

extern "C" void kernel_launch(void* const* d_in, const int* in_sizes, int n_in,
                              void* d_out, int out_size, void* d_ws, size_t ws_size,
                              hipStream_t stream) {
    const float* x      = (const float*)d_in[0];
    const int*   ei     = (const int*)d_in[1];
    const int*   batch  = (const int*)d_in[2];
    const float* W1     = (const float*)d_in[3];
    const float* a_src1 = (const float*)d_in[4];
    const float* a_dst1 = (const float*)d_in[5];
    const float* b1     = (const float*)d_in[6];
    const float* W2     = (const float*)d_in[7];
    const float* a_src2 = (const float*)d_in[8];
    const float* a_dst2 = (const float*)d_in[9];
    const float* b2     = (const float*)d_in[10];
    const float* fc_w   = (const float*)d_in[11];
    const float* fc_b   = (const float*)d_in[12];
    float* out = (float*)d_out;

    const int N = in_sizes[2];
    const int E = in_sizes[1] / 2;
    const int F_in = in_sizes[0] / N;   // 128
    const int D1 = HEADS * 64;          // 256
    const int D2 = HEADS * 16;          // 64

    const int* src = ei;
    const int* dst = ei + E;

    // workspace layout (h2/as2/ad2/g2 overlay h1, which dies after layer-1 agg)
    char* w = (char*)d_ws;
    size_t off = 0;
    auto alloc = [&](size_t bytes) {
        size_t p = off;
        off = align_up(off + bytes, 256);
        return (void*)(w + p);
    };
    int* deg    = (int*)alloc((size_t)N * 4);
    int* ofs    = (int*)alloc((size_t)(N + 1) * 4);
    int* cursor = (int*)alloc((size_t)N * 4);
    int* csr    = (int*)alloc((size_t)(E + N) * 4);
    int* bstart = (int*)alloc(65 * 4);
    float* pooled = (float*)alloc(64 * 64 * 4);
    float* as1  = (float*)alloc((size_t)N * HEADS * 4);
    float* ad1  = (float*)alloc((size_t)N * HEADS * 4);
    float* g1   = (float*)alloc((size_t)N * D1 * 4);
    // h1 region; after layer-1 agg reused for h2/as2/ad2/g2
    char* h1base = (char*)alloc((size_t)N * D1 * 4);
    float* h1 = (float*)h1base;
    float* h2  = (float*)h1base;                                   // [N, 64]
    float* as2 = (float*)(h1base + align_up((size_t)N * D2 * 4, 256));
    float* ad2 = (float*)((char*)as2 + align_up((size_t)N * HEADS * 4, 256));
    float* g2  = (float*)((char*)ad2 + align_up((size_t)N * HEADS * 4, 256));

    // --- CSR build ---
    init_deg_k<<<(N + 255) / 256, 256, 0, stream>>>(deg, N);
    count_deg_k<<<(E + 255) / 256, 256, 0, stream>>>(dst, deg, E);
    scan_deg_k<<<1, 1024, 0, stream>>>(deg, ofs, cursor, N);
    scatter_k<<<(E + N + 255) / 256, 256, 0, stream>>>(src, dst, cursor, csr, E, N);

    // --- layer 1 ---
    {
        dim3 grid(D1 / 64, (N + 63) / 64);
        sgemm_k<<<grid, dim3(16, 16), 0, stream>>>(x, W1, h1, N, D1, F_in);
    }
    alphas_k<64><<<(N * HEADS + 255) / 256, 256, 0, stream>>>(h1, a_src1, a_dst1, as1, ad1, N);
    gat_agg_k<64><<<N, 256, 0, stream>>>(h1, as1, ad1, ofs, csr, b1, g1, N);

    // --- layer 2 ---
    {
        dim3 grid(D2 / 64, (N + 63) / 64);
        sgemm_k<<<grid, dim3(16, 16), 0, stream>>>(g1, W2, h2, N, D2, D1);
    }
    alphas_k<16><<<(N * HEADS + 255) / 256, 256, 0, stream>>>(h2, a_src2, a_dst2, as2, ad2, N);
    gat_agg_k<16><<<N, 64, 0, stream>>>(h2, as2, ad2, ofs, csr, b2, g2, N);

    // --- pool + fc ---
    graph_bounds_k<<<1, 128, 0, stream>>>(batch, N, bstart);
    pool_zero_k<<<16, 256, 0, stream>>>(pooled);
    pool_sum_k<<<(N + 255) / 256, 256, 0, stream>>>(g2, batch, pooled, N);
    fc_k<<<64, 32, 0, stream>>>(pooled, bstart, fc_w, fc_b, out);
}

// Round 3
// 573.689 us; speedup vs baseline: 1.4041x; 1.0674x over previous
//
#include <hip/hip_runtime.h>
#include <hip/hip_bf16.h>
#include <hip/hip_fp16.h>
#include <math.h>

#define HEADS 4

// ---------------- CSR build ----------------

__global__ void init_deg_k(int* deg, int N) {
    int i = blockIdx.x * blockDim.x + threadIdx.x;
    if (i < N) deg[i] = 1;  // self loop
}

__global__ void count_deg_k(const int* __restrict__ dst, int* __restrict__ deg, int E) {
    int i = blockIdx.x * blockDim.x + threadIdx.x;
    if (i < E) atomicAdd(&deg[dst[i]], 1);
}

__global__ void scan_deg_k(const int* __restrict__ deg, int* __restrict__ ofs,
                           int* __restrict__ cursor, int N) {
    __shared__ int s[1024];
    int t = threadIdx.x;
    int chunk = (N + 1023) / 1024;
    int b = t * chunk;
    int e = min(b + chunk, N);
    int sum = 0;
    for (int i = b; i < e; i++) sum += deg[i];
    s[t] = sum;
    __syncthreads();
    for (int off = 1; off < 1024; off <<= 1) {
        int v = 0;
        if (t >= off) v = s[t - off];
        __syncthreads();
        s[t] += v;
        __syncthreads();
    }
    int run = (t == 0) ? 0 : s[t - 1];
    for (int i = b; i < e; i++) {
        ofs[i] = run; cursor[i] = run;
        run += deg[i];
    }
    if (t == 1023) ofs[N] = s[1023];
}

__global__ void scatter_k(const int* __restrict__ src, const int* __restrict__ dst,
                          int* __restrict__ cursor, int* __restrict__ csr, int E, int N) {
    int i = blockIdx.x * blockDim.x + threadIdx.x;
    if (i < E) {
        int d = dst[i];
        int p = atomicAdd(&cursor[d], 1);
        csr[p] = src[i];
    } else if (i < E + N) {
        int n = i - E;
        int p = atomicAdd(&cursor[n], 1);
        csr[p] = n;
    }
}

// ---------------- fp32 tiled GEMM: C = A[M,K] @ B[K,Nn] ----------------
// BM=BN=64, BK=32, block (16,16), 4x4 per thread. Nn % 64 == 0, K % 32 == 0.
// FUSE=true (layer 1): tile col range = one head; write fp16 h, fused
// alpha_src/alpha_dst dot products via 16-lane shuffle reduction. No fp32 C.

template <bool FUSE>
__global__ __launch_bounds__(256) void sgemm_k(const float* __restrict__ A,
                                               const float* __restrict__ B,
                                               float* __restrict__ C_,
                                               int M, int Nn, int K,
                                               __half* __restrict__ hout,
                                               const float* __restrict__ avs,
                                               const float* __restrict__ avd,
                                               float* __restrict__ os,
                                               float* __restrict__ od) {
    constexpr int BM = 64, BN = 64, BK = 32;
    __shared__ float As[BK][BM + 4];
    __shared__ float Bs[BK][BN];
    int tx = threadIdx.x, ty = threadIdx.y;
    int tid = ty * 16 + tx;
    int row0 = blockIdx.y * BM;
    int col0 = blockIdx.x * BN;
    float acc[4][4] = {};
    for (int k0 = 0; k0 < K; k0 += BK) {
        constexpr int AF4 = BM * BK / 4;  // 512
        #pragma unroll
        for (int f = tid; f < AF4; f += 256) {
            int r = f / (BK / 4);
            int c4 = f % (BK / 4);
            int gr = row0 + r;
            float4 v = make_float4(0.f, 0.f, 0.f, 0.f);
            if (gr < M) v = *(const float4*)(A + (size_t)gr * K + k0 + c4 * 4);
            As[c4 * 4 + 0][r] = v.x;
            As[c4 * 4 + 1][r] = v.y;
            As[c4 * 4 + 2][r] = v.z;
            As[c4 * 4 + 3][r] = v.w;
        }
        constexpr int BF4 = BK * BN / 4;  // 512
        #pragma unroll
        for (int f = tid; f < BF4; f += 256) {
            int r = f / (BN / 4);
            int c4 = f % (BN / 4);
            *(float4*)(&Bs[r][c4 * 4]) = *(const float4*)(B + (size_t)(k0 + r) * Nn + col0 + c4 * 4);
        }
        __syncthreads();
        #pragma unroll
        for (int k = 0; k < BK; k++) {
            float a4[4], b4[4];
            *(float4*)a4 = *(const float4*)&As[k][ty * 4];
            *(float4*)b4 = *(const float4*)&Bs[k][tx * 4];
            #pragma unroll
            for (int i = 0; i < 4; i++)
                #pragma unroll
                for (int j = 0; j < 4; j++)
                    acc[i][j] = fmaf(a4[i], b4[j], acc[i][j]);
        }
        __syncthreads();
    }
    if (!FUSE) {
        #pragma unroll
        for (int i = 0; i < 4; i++) {
            int gr = row0 + ty * 4 + i;
            if (gr < M) {
                *(float4*)(C_ + (size_t)gr * Nn + col0 + tx * 4) =
                    make_float4(acc[i][0], acc[i][1], acc[i][2], acc[i][3]);
            }
        }
    } else {
        int h = col0 >> 6;  // head index; channel within head = tx*4+j
        float as4[4], ad4[4];
        #pragma unroll
        for (int j = 0; j < 4; j++) {
            as4[j] = avs[h * 64 + tx * 4 + j];
            ad4[j] = avd[h * 64 + tx * 4 + j];
        }
        #pragma unroll
        for (int i = 0; i < 4; i++) {
            int gr = row0 + ty * 4 + i;
            float ps = 0.f, pd = 0.f;
            #pragma unroll
            for (int j = 0; j < 4; j++) {
                ps = fmaf(acc[i][j], as4[j], ps);
                pd = fmaf(acc[i][j], ad4[j], pd);
            }
            #pragma unroll
            for (int o = 8; o >= 1; o >>= 1) {
                ps += __shfl_down(ps, o, 16);
                pd += __shfl_down(pd, o, 16);
            }
            if (gr < M) {
                if (tx == 0) {
                    os[(size_t)gr * HEADS + h] = ps;
                    od[(size_t)gr * HEADS + h] = pd;
                }
                __half2* hp2 = (__half2*)(hout + (size_t)gr * Nn + col0 + tx * 4);
                hp2[0] = __floats2half2_rn(acc[i][0], acc[i][1]);
                hp2[1] = __floats2half2_rn(acc[i][2], acc[i][3]);
            }
        }
    }
}

// ---------------- GAT aggregation layer 1 (C=64, fp16 gather) ----------------
// One block per dst node; wave w = head w; lane = channel. Barrier-free:
// edge alpha state lives in registers, broadcast via __shfl.

__global__ __launch_bounds__(256) void gat_agg64_f16_k(
    const __half* __restrict__ hsrc,  // [N, 256] fp16
    const float* __restrict__ as,     // [N, 4]
    const float* __restrict__ ad,     // [N, 4]
    const int* __restrict__ ofs,
    const int* __restrict__ csr,
    const float* __restrict__ bias,   // [256]
    float* __restrict__ out, int N) {
    int i = blockIdx.x;
    int t = threadIdx.x;
    int w = t >> 6;       // head
    int lane = t & 63;    // channel
    int beg = ofs[i], end = ofs[i + 1];
    float adh = ad[(size_t)i * HEADS + w];
    float m = -INFINITY, l = 0.f, accv = 0.f;
    for (int base = beg; base < end; base += 64) {
        int cl = min(64, end - base);
        int s = 0;
        float e = -INFINITY;
        if (lane < cl) {
            s = csr[base + lane];
            float a = as[(size_t)s * HEADS + w];
            e = a + adh;
            e = (e > 0.f) ? e : 0.2f * e;
        }
        float cmax = e;
        #pragma unroll
        for (int o = 32; o >= 1; o >>= 1) cmax = fmaxf(cmax, __shfl_xor(cmax, o));
        float m_new = fmaxf(m, cmax);
        float p = (lane < cl) ? __expf(e - m_new) : 0.f;
        float sum = p;
        #pragma unroll
        for (int o = 32; o >= 1; o >>= 1) sum += __shfl_xor(sum, o);
        float sc = __expf(m - m_new);  // 0 on first chunk (m=-inf)
        l = l * sc + sum;
        m = m_new;
        accv *= sc;
        int j = 0;
        for (; j + 4 <= cl; j += 4) {
            float p0 = __shfl(p, j), p1 = __shfl(p, j + 1);
            float p2 = __shfl(p, j + 2), p3 = __shfl(p, j + 3);
            int s0 = __shfl(s, j), s1 = __shfl(s, j + 1);
            int s2 = __shfl(s, j + 2), s3 = __shfl(s, j + 3);
            float v0 = __half2float(hsrc[(size_t)s0 * 256 + t]);
            float v1 = __half2float(hsrc[(size_t)s1 * 256 + t]);
            float v2 = __half2float(hsrc[(size_t)s2 * 256 + t]);
            float v3 = __half2float(hsrc[(size_t)s3 * 256 + t]);
            accv = fmaf(p0, v0, accv);
            accv = fmaf(p1, v1, accv);
            accv = fmaf(p2, v2, accv);
            accv = fmaf(p3, v3, accv);
        }
        for (; j < cl; j++) {
            float pj = __shfl(p, j);
            int sj = __shfl(s, j);
            accv = fmaf(pj, __half2float(hsrc[(size_t)sj * 256 + t]), accv);
        }
    }
    float r = accv / l + bias[t];
    out[(size_t)i * 256 + t] = fmaxf(r, 0.f);
}

// ---------------- GAT aggregation layer 2 (C=16, fp32) ----------------
// 4 nodes per block (wave per node); within a wave lane = head*16+chan,
// 16-lane subgroup shuffles for per-head softmax, chunk of 16 edges.

__global__ __launch_bounds__(256) void gat_agg16_k(
    const float* __restrict__ hsrc,   // [N, 64]
    const float* __restrict__ as,
    const float* __restrict__ ad,
    const int* __restrict__ ofs,
    const int* __restrict__ csr,
    const float* __restrict__ bias,   // [64]
    float* __restrict__ out, int N) {
    int node = blockIdx.x * 4 + (threadIdx.x >> 6);
    if (node >= N) return;
    int lane = threadIdx.x & 63;
    int h = lane >> 4;
    int je = lane & 15;
    int beg = ofs[node], end = ofs[node + 1];
    float adh = ad[(size_t)node * HEADS + h];
    float m = -INFINITY, l = 0.f, accv = 0.f;
    for (int base = beg; base < end; base += 16) {
        int cl = min(16, end - base);
        int s = 0;
        float e = -INFINITY;
        if (je < cl) {
            s = csr[base + je];
            float a = as[(size_t)s * HEADS + h];
            e = a + adh;
            e = (e > 0.f) ? e : 0.2f * e;
        }
        float cmax = e;
        #pragma unroll
        for (int o = 8; o >= 1; o >>= 1) cmax = fmaxf(cmax, __shfl_xor(cmax, o));
        float m_new = fmaxf(m, cmax);
        float p = (je < cl) ? __expf(e - m_new) : 0.f;
        float sum = p;
        #pragma unroll
        for (int o = 8; o >= 1; o >>= 1) sum += __shfl_xor(sum, o);
        float sc = __expf(m - m_new);
        l = l * sc + sum;
        m = m_new;
        accv *= sc;
        int j = 0;
        for (; j + 4 <= cl; j += 4) {
            float p0 = __shfl(p, h * 16 + j), p1 = __shfl(p, h * 16 + j + 1);
            float p2 = __shfl(p, h * 16 + j + 2), p3 = __shfl(p, h * 16 + j + 3);
            int s0 = __shfl(s, h * 16 + j), s1 = __shfl(s, h * 16 + j + 1);
            int s2 = __shfl(s, h * 16 + j + 2), s3 = __shfl(s, h * 16 + j + 3);
            float v0 = hsrc[(size_t)s0 * 64 + lane];
            float v1 = hsrc[(size_t)s1 * 64 + lane];
            float v2 = hsrc[(size_t)s2 * 64 + lane];
            float v3 = hsrc[(size_t)s3 * 64 + lane];
            accv = fmaf(p0, v0, accv);
            accv = fmaf(p1, v1, accv);
            accv = fmaf(p2, v2, accv);
            accv = fmaf(p3, v3, accv);
        }
        for (; j < cl; j++) {
            float pj = __shfl(p, h * 16 + j);
            int sj = __shfl(s, h * 16 + j);
            accv = fmaf(pj, hsrc[(size_t)sj * 64 + lane], accv);
        }
    }
    float r = accv / l + bias[lane];
    out[(size_t)node * 64 + lane] = fmaxf(r, 0.f);
}

// ---------------- alpha dots for layer 2 ----------------

template <int C>
__global__ void alphas_k(const float* __restrict__ hmat, const float* __restrict__ avs,
                         const float* __restrict__ avd, float* __restrict__ os,
                         float* __restrict__ od, int N) {
    int idx = blockIdx.x * blockDim.x + threadIdx.x;
    if (idx >= N * HEADS) return;
    int n = idx >> 2, h = idx & 3;
    const float4* hp = (const float4*)(hmat + (size_t)n * HEADS * C + h * C);
    const float4* sp = (const float4*)(avs + h * C);
    const float4* dp = (const float4*)(avd + h * C);
    float ss = 0.f, sd = 0.f;
    #pragma unroll
    for (int k = 0; k < C / 4; k++) {
        float4 hv = hp[k], sv = sp[k], dv = dp[k];
        ss += hv.x * sv.x + hv.y * sv.y + hv.z * sv.z + hv.w * sv.w;
        sd += hv.x * dv.x + hv.y * dv.y + hv.z * dv.z + hv.w * dv.w;
    }
    os[idx] = ss;
    od[idx] = sd;
}

// ---------------- pooling + FC ----------------

__global__ void graph_bounds_k(const int* __restrict__ batch, int N, int* __restrict__ bstart) {
    int g = threadIdx.x;
    if (g <= 64) {
        int lo = 0, hi = N;
        while (lo < hi) {
            int mid = (lo + hi) >> 1;
            if (batch[mid] < g) lo = mid + 1; else hi = mid;
        }
        bstart[g] = lo;
    }
}

__global__ void pool_zero_k(float* __restrict__ sums) {
    sums[blockIdx.x * blockDim.x + threadIdx.x] = 0.f;
}

__global__ __launch_bounds__(256) void pool_sum_k(const float* __restrict__ g2,
                                                  const int* __restrict__ batch,
                                                  float* __restrict__ sums, int N) {
    int c = threadIdx.x & 63;
    int r = threadIdx.x >> 6;
    int base = blockIdx.x * 256;
    int lim = min(base + 256, N);
    float acc = 0.f;
    int cur = -1;
    for (int n = base + r; n < lim; n += 4) {
        int g = batch[n];
        if (g != cur) {
            if (cur >= 0) atomicAdd(&sums[cur * 64 + c], acc);
            acc = 0.f;
            cur = g;
        }
        acc += g2[(size_t)n * 64 + c];
    }
    if (cur >= 0) atomicAdd(&sums[cur * 64 + c], acc);
}

__global__ void fc_k(const float* __restrict__ sums, const int* __restrict__ bstart,
                     const float* __restrict__ w, const float* __restrict__ b,
                     float* __restrict__ out) {
    int g = blockIdx.x, o = threadIdx.x;  // 32 threads
    float cnt = (float)max(bstart[g + 1] - bstart[g], 1);
    float inv = 1.f / cnt;
    float acc = b[o];
    for (int k = 0; k < 64; k++) acc = fmaf(sums[g * 64 + k] * inv, w[k * 32 + o], acc);
    out[g * 32 + o] = acc;
}

// ---------------- launch ----------------

static inline size_t align_up(size_t x, size_t a) { return (x + a - 1) & ~(a - 1); }

extern "C" void kernel_launch(void* const* d_in, const int* in_sizes, int n_in,
                              void* d_out, int out_size, void* d_ws, size_t ws_size,
                              hipStream_t stream) {
    const float* x      = (const float*)d_in[0];
    const int*   ei     = (const int*)d_in[1];
    const int*   batch  = (const int*)d_in[2];
    const float* W1     = (const float*)d_in[3];
    const float* a_src1 = (const float*)d_in[4];
    const float* a_dst1 = (const float*)d_in[5];
    const float* b1     = (const float*)d_in[6];
    const float* W2     = (const float*)d_in[7];
    const float* a_src2 = (const float*)d_in[8];
    const float* a_dst2 = (const float*)d_in[9];
    const float* b2     = (const float*)d_in[10];
    const float* fc_w   = (const float*)d_in[11];
    const float* fc_b   = (const float*)d_in[12];
    float* out = (float*)d_out;

    const int N = in_sizes[2];
    const int E = in_sizes[1] / 2;
    const int F_in = in_sizes[0] / N;   // 128
    const int D1 = HEADS * 64;          // 256
    const int D2 = HEADS * 16;          // 64

    const int* src = ei;
    const int* dst = ei + E;

    char* w = (char*)d_ws;
    size_t off = 0;
    auto alloc = [&](size_t bytes) {
        size_t p = off;
        off = align_up(off + bytes, 256);
        return (void*)(w + p);
    };
    int* deg    = (int*)alloc((size_t)N * 4);
    int* ofs    = (int*)alloc((size_t)(N + 1) * 4);
    int* cursor = (int*)alloc((size_t)N * 4);
    int* csr    = (int*)alloc((size_t)(E + N) * 4);
    int* bstart = (int*)alloc(65 * 4);
    float* pooled = (float*)alloc(64 * 64 * 4);
    float* as1  = (float*)alloc((size_t)N * HEADS * 4);
    float* ad1  = (float*)alloc((size_t)N * HEADS * 4);
    float* g1   = (float*)alloc((size_t)N * D1 * 4);
    __half* h1h = (__half*)alloc((size_t)N * D1 * 2);   // fp16 layer-1 features
    float* h2   = (float*)alloc((size_t)N * D2 * 4);
    float* as2  = (float*)alloc((size_t)N * HEADS * 4);
    float* ad2  = (float*)alloc((size_t)N * HEADS * 4);
    float* g2   = (float*)alloc((size_t)N * D2 * 4);

    // --- CSR build ---
    init_deg_k<<<(N + 255) / 256, 256, 0, stream>>>(deg, N);
    count_deg_k<<<(E + 255) / 256, 256, 0, stream>>>(dst, deg, E);
    scan_deg_k<<<1, 1024, 0, stream>>>(deg, ofs, cursor, N);
    scatter_k<<<(E + N + 255) / 256, 256, 0, stream>>>(src, dst, cursor, csr, E, N);

    // --- layer 1: GEMM + fused fp16 store + fused alpha dots ---
    {
        dim3 grid(D1 / 64, (N + 63) / 64);
        sgemm_k<true><<<grid, dim3(16, 16), 0, stream>>>(
            x, W1, nullptr, N, D1, F_in, h1h, a_src1, a_dst1, as1, ad1);
    }
    gat_agg64_f16_k<<<N, 256, 0, stream>>>(h1h, as1, ad1, ofs, csr, b1, g1, N);

    // --- layer 2 ---
    {
        dim3 grid(D2 / 64, (N + 63) / 64);
        sgemm_k<false><<<grid, dim3(16, 16), 0, stream>>>(
            g1, W2, h2, N, D2, D1, nullptr, nullptr, nullptr, nullptr, nullptr);
    }
    alphas_k<16><<<(N * HEADS + 255) / 256, 256, 0, stream>>>(h2, a_src2, a_dst2, as2, ad2, N);
    gat_agg16_k<<<(N + 3) / 4, 256, 0, stream>>>(h2, as2, ad2, ofs, csr, b2, g2, N);

    // --- pool + fc ---
    graph_bounds_k<<<1, 128, 0, stream>>>(batch, N, bstart);
    pool_zero_k<<<16, 256, 0, stream>>>(pooled);
    pool_sum_k<<<(N + 255) / 256, 256, 0, stream>>>(g2, batch, pooled, N);
    fc_k<<<64, 32, 0, stream>>>(pooled, bstart, fc_w, fc_b, out);
}

// Round 4
// 496.745 us; speedup vs baseline: 1.6215x; 1.1549x over previous
//
#include <hip/hip_runtime.h>
#include <hip/hip_bf16.h>
#include <hip/hip_fp16.h>
#include <math.h>

#define HEADS 4

// ---------------- CSR build ----------------

__global__ void init_deg_k(int* deg, int N) {
    int i = blockIdx.x * blockDim.x + threadIdx.x;
    if (i < N) deg[i] = 1;  // self loop
}

__global__ void count_deg_k(const int* __restrict__ dst, int* __restrict__ deg, int E) {
    int i = blockIdx.x * blockDim.x + threadIdx.x;
    if (i < E) atomicAdd(&deg[dst[i]], 1);
}

__global__ void scan_deg_k(const int* __restrict__ deg, int* __restrict__ ofs,
                           int* __restrict__ cursor, int N) {
    __shared__ int s[1024];
    int t = threadIdx.x;
    int chunk = (N + 1023) / 1024;
    int b = t * chunk;
    int e = min(b + chunk, N);
    int sum = 0;
    for (int i = b; i < e; i++) sum += deg[i];
    s[t] = sum;
    __syncthreads();
    for (int off = 1; off < 1024; off <<= 1) {
        int v = 0;
        if (t >= off) v = s[t - off];
        __syncthreads();
        s[t] += v;
        __syncthreads();
    }
    int run = (t == 0) ? 0 : s[t - 1];
    for (int i = b; i < e; i++) {
        ofs[i] = run; cursor[i] = run;
        run += deg[i];
    }
    if (t == 1023) ofs[N] = s[1023];
}

__global__ void scatter_k(const int* __restrict__ src, const int* __restrict__ dst,
                          int* __restrict__ cursor, int* __restrict__ csr, int E, int N) {
    int i = blockIdx.x * blockDim.x + threadIdx.x;
    if (i < E) {
        int d = dst[i];
        int p = atomicAdd(&cursor[d], 1);
        csr[p] = src[i];
    } else if (i < E + N) {
        int n = i - E;
        int p = atomicAdd(&cursor[n], 1);
        csr[p] = n;
    }
}

// ---------------- fp32 tiled GEMM: C = A[M,K] @ B[K,Nn] ----------------
// BM=BN=64, BK=32, block (16,16), 4x4 per thread.
// MODE 0: plain fp32 C.  MODE 1: layer-1 fuse (64ch/head): fp16 h + alpha dots
// via 16-lane shuffle.  MODE 2: layer-2 fuse (16ch/head, Nn=64): fp16 h +
// alpha dots via 4-lane shuffle.

template <int MODE>
__global__ __launch_bounds__(256) void sgemm_k(const float* __restrict__ A,
                                               const float* __restrict__ B,
                                               float* __restrict__ C_,
                                               int M, int Nn, int K,
                                               __half* __restrict__ hout,
                                               const float* __restrict__ avs,
                                               const float* __restrict__ avd,
                                               float* __restrict__ os,
                                               float* __restrict__ od) {
    constexpr int BM = 64, BN = 64, BK = 32;
    __shared__ float As[BK][BM + 4];
    __shared__ float Bs[BK][BN];
    int tx = threadIdx.x, ty = threadIdx.y;
    int tid = ty * 16 + tx;
    int row0 = blockIdx.y * BM;
    int col0 = blockIdx.x * BN;
    float acc[4][4] = {};
    for (int k0 = 0; k0 < K; k0 += BK) {
        constexpr int AF4 = BM * BK / 4;  // 512
        #pragma unroll
        for (int f = tid; f < AF4; f += 256) {
            int r = f / (BK / 4);
            int c4 = f % (BK / 4);
            int gr = row0 + r;
            float4 v = make_float4(0.f, 0.f, 0.f, 0.f);
            if (gr < M) v = *(const float4*)(A + (size_t)gr * K + k0 + c4 * 4);
            As[c4 * 4 + 0][r] = v.x;
            As[c4 * 4 + 1][r] = v.y;
            As[c4 * 4 + 2][r] = v.z;
            As[c4 * 4 + 3][r] = v.w;
        }
        constexpr int BF4 = BK * BN / 4;  // 512
        #pragma unroll
        for (int f = tid; f < BF4; f += 256) {
            int r = f / (BN / 4);
            int c4 = f % (BN / 4);
            *(float4*)(&Bs[r][c4 * 4]) = *(const float4*)(B + (size_t)(k0 + r) * Nn + col0 + c4 * 4);
        }
        __syncthreads();
        #pragma unroll
        for (int k = 0; k < BK; k++) {
            float a4[4], b4[4];
            *(float4*)a4 = *(const float4*)&As[k][ty * 4];
            *(float4*)b4 = *(const float4*)&Bs[k][tx * 4];
            #pragma unroll
            for (int i = 0; i < 4; i++)
                #pragma unroll
                for (int j = 0; j < 4; j++)
                    acc[i][j] = fmaf(a4[i], b4[j], acc[i][j]);
        }
        __syncthreads();
    }
    if (MODE == 0) {
        #pragma unroll
        for (int i = 0; i < 4; i++) {
            int gr = row0 + ty * 4 + i;
            if (gr < M) {
                *(float4*)(C_ + (size_t)gr * Nn + col0 + tx * 4) =
                    make_float4(acc[i][0], acc[i][1], acc[i][2], acc[i][3]);
            }
        }
    } else if (MODE == 1) {
        int h = col0 >> 6;  // head; channel within head = tx*4+j
        float as4[4], ad4[4];
        #pragma unroll
        for (int j = 0; j < 4; j++) {
            as4[j] = avs[h * 64 + tx * 4 + j];
            ad4[j] = avd[h * 64 + tx * 4 + j];
        }
        #pragma unroll
        for (int i = 0; i < 4; i++) {
            int gr = row0 + ty * 4 + i;
            float ps = 0.f, pd = 0.f;
            #pragma unroll
            for (int j = 0; j < 4; j++) {
                ps = fmaf(acc[i][j], as4[j], ps);
                pd = fmaf(acc[i][j], ad4[j], pd);
            }
            #pragma unroll
            for (int o = 8; o >= 1; o >>= 1) {
                ps += __shfl_down(ps, o, 16);
                pd += __shfl_down(pd, o, 16);
            }
            if (gr < M) {
                if (tx == 0) {
                    os[(size_t)gr * HEADS + h] = ps;
                    od[(size_t)gr * HEADS + h] = pd;
                }
                __half2* hp2 = (__half2*)(hout + (size_t)gr * Nn + col0 + tx * 4);
                hp2[0] = __floats2half2_rn(acc[i][0], acc[i][1]);
                hp2[1] = __floats2half2_rn(acc[i][2], acc[i][3]);
            }
        }
    } else {  // MODE 2: Nn == 64, col0 == 0, head = tx>>2, chan-in-head = (tx&3)*4+j
        int h = tx >> 2;
        int cih = (tx & 3) * 4;
        float as4[4], ad4[4];
        #pragma unroll
        for (int j = 0; j < 4; j++) {
            as4[j] = avs[h * 16 + cih + j];
            ad4[j] = avd[h * 16 + cih + j];
        }
        #pragma unroll
        for (int i = 0; i < 4; i++) {
            int gr = row0 + ty * 4 + i;
            float ps = 0.f, pd = 0.f;
            #pragma unroll
            for (int j = 0; j < 4; j++) {
                ps = fmaf(acc[i][j], as4[j], ps);
                pd = fmaf(acc[i][j], ad4[j], pd);
            }
            ps += __shfl_down(ps, 2, 4); ps += __shfl_down(ps, 1, 4);
            pd += __shfl_down(pd, 2, 4); pd += __shfl_down(pd, 1, 4);
            if (gr < M) {
                if ((tx & 3) == 0) {
                    os[(size_t)gr * HEADS + h] = ps;
                    od[(size_t)gr * HEADS + h] = pd;
                }
                __half2* hp2 = (__half2*)(hout + (size_t)gr * 64 + tx * 4);
                hp2[0] = __floats2half2_rn(acc[i][0], acc[i][1]);
                hp2[1] = __floats2half2_rn(acc[i][2], acc[i][3]);
            }
        }
    }
}

// ---------------- GAT aggregation layer 1 (C=64, fp16 gather) ----------------
// One WAVE per node (4 nodes/block). Lane l owns channels [4l,4l+4) (head l>>4).
// Alpha softmax: lane l computes edge (l&15) of head (l>>4) on 16-lane subgroup.
// Gather: one dwordx2 per lane per edge = full 512B row per wave-instruction.

__global__ __launch_bounds__(256) void gat_agg64_f16_k(
    const __half* __restrict__ hsrc,  // [N, 256] fp16
    const float* __restrict__ as,     // [N, 4]
    const float* __restrict__ ad,     // [N, 4]
    const int* __restrict__ ofs,
    const int* __restrict__ csr,
    const float* __restrict__ bias,   // [256]
    float* __restrict__ out, int N) {
    int node = blockIdx.x * 4 + (threadIdx.x >> 6);
    if (node >= N) return;
    int l = threadIdx.x & 63;
    int h = l >> 4;       // head of my channels AND my alpha subgroup
    int je = l & 15;      // alpha edge slot
    int hb = h << 4;
    int beg = ofs[node], end = ofs[node + 1];
    float adh = ad[(size_t)node * HEADS + h];
    float4 bv = *(const float4*)(bias + l * 4);
    float m = -INFINITY, den = 0.f;
    float4 acc = make_float4(0.f, 0.f, 0.f, 0.f);
    for (int base = beg; base < end; base += 16) {
        int cl = min(16, end - base);
        int s = 0;
        float e = -INFINITY;
        if (je < cl) {
            s = csr[base + je];
            float a = as[(size_t)s * HEADS + h] + adh;
            e = (a > 0.f) ? a : 0.2f * a;
        }
        float cmax = e;
        #pragma unroll
        for (int o = 8; o >= 1; o >>= 1) cmax = fmaxf(cmax, __shfl_xor(cmax, o));
        float m_new = fmaxf(m, cmax);
        float p = (je < cl) ? __expf(e - m_new) : 0.f;
        float sum = p;
        #pragma unroll
        for (int o = 8; o >= 1; o >>= 1) sum += __shfl_xor(sum, o);
        float sc = __expf(m - m_new);  // 0 on first chunk
        den = den * sc + sum;
        m = m_new;
        acc.x *= sc; acc.y *= sc; acc.z *= sc; acc.w *= sc;
        int j = 0;
        for (; j + 4 <= cl; j += 4) {
            float p0 = __shfl(p, hb + j),     p1 = __shfl(p, hb + j + 1);
            float p2 = __shfl(p, hb + j + 2), p3 = __shfl(p, hb + j + 3);
            int s0 = __shfl(s, hb + j),     s1 = __shfl(s, hb + j + 1);
            int s2 = __shfl(s, hb + j + 2), s3 = __shfl(s, hb + j + 3);
            uint2 r0 = *(const uint2*)(hsrc + (size_t)s0 * 256 + l * 4);
            uint2 r1 = *(const uint2*)(hsrc + (size_t)s1 * 256 + l * 4);
            uint2 r2 = *(const uint2*)(hsrc + (size_t)s2 * 256 + l * 4);
            uint2 r3 = *(const uint2*)(hsrc + (size_t)s3 * 256 + l * 4);
            float2 a0 = __half22float2(*(__half2*)&r0.x), b0 = __half22float2(*(__half2*)&r0.y);
            float2 a1 = __half22float2(*(__half2*)&r1.x), b1 = __half22float2(*(__half2*)&r1.y);
            float2 a2 = __half22float2(*(__half2*)&r2.x), b2 = __half22float2(*(__half2*)&r2.y);
            float2 a3 = __half22float2(*(__half2*)&r3.x), b3 = __half22float2(*(__half2*)&r3.y);
            acc.x = fmaf(p0, a0.x, acc.x); acc.y = fmaf(p0, a0.y, acc.y);
            acc.z = fmaf(p0, b0.x, acc.z); acc.w = fmaf(p0, b0.y, acc.w);
            acc.x = fmaf(p1, a1.x, acc.x); acc.y = fmaf(p1, a1.y, acc.y);
            acc.z = fmaf(p1, b1.x, acc.z); acc.w = fmaf(p1, b1.y, acc.w);
            acc.x = fmaf(p2, a2.x, acc.x); acc.y = fmaf(p2, a2.y, acc.y);
            acc.z = fmaf(p2, b2.x, acc.z); acc.w = fmaf(p2, b2.y, acc.w);
            acc.x = fmaf(p3, a3.x, acc.x); acc.y = fmaf(p3, a3.y, acc.y);
            acc.z = fmaf(p3, b3.x, acc.z); acc.w = fmaf(p3, b3.y, acc.w);
        }
        for (; j < cl; j++) {
            float pj = __shfl(p, hb + j);
            int sj = __shfl(s, hb + j);
            uint2 r0 = *(const uint2*)(hsrc + (size_t)sj * 256 + l * 4);
            float2 a0 = __half22float2(*(__half2*)&r0.x), b0 = __half22float2(*(__half2*)&r0.y);
            acc.x = fmaf(pj, a0.x, acc.x); acc.y = fmaf(pj, a0.y, acc.y);
            acc.z = fmaf(pj, b0.x, acc.z); acc.w = fmaf(pj, b0.y, acc.w);
        }
    }
    float inv = 1.f / den;
    float4 r;
    r.x = fmaxf(fmaf(acc.x, inv, bv.x), 0.f);
    r.y = fmaxf(fmaf(acc.y, inv, bv.y), 0.f);
    r.z = fmaxf(fmaf(acc.z, inv, bv.z), 0.f);
    r.w = fmaxf(fmaf(acc.w, inv, bv.w), 0.f);
    *(float4*)(out + (size_t)node * 256 + l * 4) = r;
}

// ---------------- GAT aggregation layer 2 (C=16, fp16 gather) ----------------
// One WAVE per node. Lane l: row position q=l&15 -> channels [4q,4q+4) of the
// 64-ch row (head hh=q>>2); edge subslot eg=l>>4 (4 edges per load instr).
// Alpha: lane l computes edge (l&15) of head (l>>4) on 16-lane subgroup.

__global__ __launch_bounds__(256) void gat_agg16_f16_k(
    const __half* __restrict__ hsrc,  // [N, 64] fp16
    const float* __restrict__ as,
    const float* __restrict__ ad,
    const int* __restrict__ ofs,
    const int* __restrict__ csr,
    const float* __restrict__ bias,   // [64]
    float* __restrict__ out, int N) {
    int node = blockIdx.x * 4 + (threadIdx.x >> 6);
    if (node >= N) return;
    int l = threadIdx.x & 63;
    int ha = l >> 4;      // alpha subgroup head
    int je = l & 15;      // alpha edge slot
    int q = l & 15;       // row position: channels [4q,4q+4)
    int hh = q >> 2;      // head of my channels
    int eg = l >> 4;      // edge subslot
    int beg = ofs[node], end = ofs[node + 1];
    float adh = ad[(size_t)node * HEADS + ha];
    float m = -INFINITY, den = 0.f;
    float4 acc = make_float4(0.f, 0.f, 0.f, 0.f);
    for (int base = beg; base < end; base += 16) {
        int cl = min(16, end - base);
        int s = 0;
        float e = -INFINITY;
        if (je < cl) {
            s = csr[base + je];
            float a = as[(size_t)s * HEADS + ha] + adh;
            e = (a > 0.f) ? a : 0.2f * a;
        }
        float cmax = e;
        #pragma unroll
        for (int o = 8; o >= 1; o >>= 1) cmax = fmaxf(cmax, __shfl_xor(cmax, o));
        float m_new = fmaxf(m, cmax);
        float p = (je < cl) ? __expf(e - m_new) : 0.f;
        float sum = p;
        #pragma unroll
        for (int o = 8; o >= 1; o >>= 1) sum += __shfl_xor(sum, o);
        float sc = __expf(m - m_new);
        den = den * sc + sum;
        m = m_new;
        float sch = __shfl(sc, hh << 4);  // rescale factor of MY channel head
        acc.x *= sch; acc.y *= sch; acc.z *= sch; acc.w *= sch;
        for (int j0 = 0; j0 < cl; j0 += 4) {
            int j = j0 + eg;
            int jc = min(j, cl - 1);
            float pj = __shfl(p, (hh << 4) + jc);
            int sj = __shfl(s, (hh << 4) + jc);
            if (j < cl) {
                uint2 raw = *(const uint2*)(hsrc + (size_t)sj * 64 + q * 4);
                float2 f0 = __half22float2(*(__half2*)&raw.x);
                float2 f1 = __half22float2(*(__half2*)&raw.y);
                acc.x = fmaf(pj, f0.x, acc.x); acc.y = fmaf(pj, f0.y, acc.y);
                acc.z = fmaf(pj, f1.x, acc.z); acc.w = fmaf(pj, f1.y, acc.w);
            }
        }
    }
    // combine the 4 edge-subslot partials (lanes ±16, ±32 share q)
    acc.x += __shfl_xor(acc.x, 16); acc.y += __shfl_xor(acc.y, 16);
    acc.z += __shfl_xor(acc.z, 16); acc.w += __shfl_xor(acc.w, 16);
    acc.x += __shfl_xor(acc.x, 32); acc.y += __shfl_xor(acc.y, 32);
    acc.z += __shfl_xor(acc.z, 32); acc.w += __shfl_xor(acc.w, 32);
    float denh = __shfl(den, hh << 4);
    if (eg == 0) {
        float inv = 1.f / denh;
        float4 bv = *(const float4*)(bias + q * 4);
        float4 r;
        r.x = fmaxf(fmaf(acc.x, inv, bv.x), 0.f);
        r.y = fmaxf(fmaf(acc.y, inv, bv.y), 0.f);
        r.z = fmaxf(fmaf(acc.z, inv, bv.z), 0.f);
        r.w = fmaxf(fmaf(acc.w, inv, bv.w), 0.f);
        *(float4*)(out + (size_t)node * 64 + q * 4) = r;
    }
}

// ---------------- pooling + FC ----------------

__global__ void graph_bounds_k(const int* __restrict__ batch, int N, int* __restrict__ bstart) {
    int g = threadIdx.x;
    if (g <= 64) {
        int lo = 0, hi = N;
        while (lo < hi) {
            int mid = (lo + hi) >> 1;
            if (batch[mid] < g) lo = mid + 1; else hi = mid;
        }
        bstart[g] = lo;
    }
}

__global__ void pool_zero_k(float* __restrict__ sums) {
    sums[blockIdx.x * blockDim.x + threadIdx.x] = 0.f;
}

__global__ __launch_bounds__(256) void pool_sum_k(const float* __restrict__ g2,
                                                  const int* __restrict__ batch,
                                                  float* __restrict__ sums, int N) {
    int c = threadIdx.x & 63;
    int r = threadIdx.x >> 6;
    int base = blockIdx.x * 256;
    int lim = min(base + 256, N);
    float acc = 0.f;
    int cur = -1;
    for (int n = base + r; n < lim; n += 4) {
        int g = batch[n];
        if (g != cur) {
            if (cur >= 0) atomicAdd(&sums[cur * 64 + c], acc);
            acc = 0.f;
            cur = g;
        }
        acc += g2[(size_t)n * 64 + c];
    }
    if (cur >= 0) atomicAdd(&sums[cur * 64 + c], acc);
}

__global__ void fc_k(const float* __restrict__ sums, const int* __restrict__ bstart,
                     const float* __restrict__ w, const float* __restrict__ b,
                     float* __restrict__ out) {
    int g = blockIdx.x, o = threadIdx.x;  // 32 threads
    float cnt = (float)max(bstart[g + 1] - bstart[g], 1);
    float inv = 1.f / cnt;
    float acc = b[o];
    for (int k = 0; k < 64; k++) acc = fmaf(sums[g * 64 + k] * inv, w[k * 32 + o], acc);
    out[g * 32 + o] = acc;
}

// ---------------- launch ----------------

static inline size_t align_up(size_t x, size_t a) { return (x + a - 1) & ~(a - 1); }

extern "C" void kernel_launch(void* const* d_in, const int* in_sizes, int n_in,
                              void* d_out, int out_size, void* d_ws, size_t ws_size,
                              hipStream_t stream) {
    const float* x      = (const float*)d_in[0];
    const int*   ei     = (const int*)d_in[1];
    const int*   batch  = (const int*)d_in[2];
    const float* W1     = (const float*)d_in[3];
    const float* a_src1 = (const float*)d_in[4];
    const float* a_dst1 = (const float*)d_in[5];
    const float* b1     = (const float*)d_in[6];
    const float* W2     = (const float*)d_in[7];
    const float* a_src2 = (const float*)d_in[8];
    const float* a_dst2 = (const float*)d_in[9];
    const float* b2     = (const float*)d_in[10];
    const float* fc_w   = (const float*)d_in[11];
    const float* fc_b   = (const float*)d_in[12];
    float* out = (float*)d_out;

    const int N = in_sizes[2];
    const int E = in_sizes[1] / 2;
    const int F_in = in_sizes[0] / N;   // 128
    const int D1 = HEADS * 64;          // 256
    const int D2 = HEADS * 16;          // 64

    const int* src = ei;
    const int* dst = ei + E;

    char* w = (char*)d_ws;
    size_t off = 0;
    auto alloc = [&](size_t bytes) {
        size_t p = off;
        off = align_up(off + bytes, 256);
        return (void*)(w + p);
    };
    int* deg    = (int*)alloc((size_t)N * 4);
    int* ofs    = (int*)alloc((size_t)(N + 1) * 4);
    int* cursor = (int*)alloc((size_t)N * 4);
    int* csr    = (int*)alloc((size_t)(E + N) * 4);
    int* bstart = (int*)alloc(65 * 4);
    float* pooled = (float*)alloc(64 * 64 * 4);
    float* as1  = (float*)alloc((size_t)N * HEADS * 4);
    float* ad1  = (float*)alloc((size_t)N * HEADS * 4);
    float* as2  = (float*)alloc((size_t)N * HEADS * 4);
    float* ad2  = (float*)alloc((size_t)N * HEADS * 4);
    float* g1   = (float*)alloc((size_t)N * D1 * 4);
    __half* h1h = (__half*)alloc((size_t)N * D1 * 2);   // fp16 layer-1 features
    __half* h2h = (__half*)alloc((size_t)N * D2 * 2);   // fp16 layer-2 features
    float* g2   = (float*)alloc((size_t)N * D2 * 4);

    // --- CSR build ---
    init_deg_k<<<(N + 255) / 256, 256, 0, stream>>>(deg, N);
    count_deg_k<<<(E + 255) / 256, 256, 0, stream>>>(dst, deg, E);
    scan_deg_k<<<1, 1024, 0, stream>>>(deg, ofs, cursor, N);
    scatter_k<<<(E + N + 255) / 256, 256, 0, stream>>>(src, dst, cursor, csr, E, N);

    // --- layer 1: GEMM + fused fp16 store + fused alpha dots ---
    {
        dim3 grid(D1 / 64, (N + 63) / 64);
        sgemm_k<1><<<grid, dim3(16, 16), 0, stream>>>(
            x, W1, nullptr, N, D1, F_in, h1h, a_src1, a_dst1, as1, ad1);
    }
    gat_agg64_f16_k<<<(N + 3) / 4, 256, 0, stream>>>(h1h, as1, ad1, ofs, csr, b1, g1, N);

    // --- layer 2: GEMM + fused fp16 store + fused alpha dots ---
    {
        dim3 grid(D2 / 64, (N + 63) / 64);
        sgemm_k<2><<<grid, dim3(16, 16), 0, stream>>>(
            g1, W2, nullptr, N, D2, D1, h2h, a_src2, a_dst2, as2, ad2);
    }
    gat_agg16_f16_k<<<(N + 3) / 4, 256, 0, stream>>>(h2h, as2, ad2, ofs, csr, b2, g2, N);

    // --- pool + fc ---
    graph_bounds_k<<<1, 128, 0, stream>>>(batch, N, bstart);
    pool_zero_k<<<16, 256, 0, stream>>>(pooled);
    pool_sum_k<<<(N + 255) / 256, 256, 0, stream>>>(g2, batch, pooled, N);
    fc_k<<<64, 32, 0, stream>>>(pooled, bstart, fc_w, fc_b, out);
}

// Round 5
// 401.870 us; speedup vs baseline: 2.0044x; 1.2361x over previous
//
#include <hip/hip_runtime.h>
#include <hip/hip_bf16.h>
#include <hip/hip_fp16.h>
#include <math.h>

#define HEADS 4

// ---------------- CSR build ----------------

__global__ void init_deg_k(int* deg, int N) {
    int i = blockIdx.x * blockDim.x + threadIdx.x;
    if (i < N) deg[i] = 1;  // self loop
}

__global__ void count_deg_k(const int* __restrict__ dst, int* __restrict__ deg, int E) {
    int i = blockIdx.x * blockDim.x + threadIdx.x;
    if (i < E) atomicAdd(&deg[dst[i]], 1);
}

// ---- two-level scan: 1024 elems per block (256 thr x 4) ----

__global__ __launch_bounds__(256) void scan_part_k(const int* __restrict__ deg,
                                                   int* __restrict__ bsums, int N) {
    int t = threadIdx.x;
    int base = blockIdx.x * 1024 + t * 4;
    int s = 0;
    if (base + 3 < N) {
        int4 v = *(const int4*)(deg + base);
        s = v.x + v.y + v.z + v.w;
    } else {
        for (int k = 0; k < 4; k++) if (base + k < N) s += deg[base + k];
    }
    #pragma unroll
    for (int o = 32; o >= 1; o >>= 1) s += __shfl_down(s, o);
    __shared__ int sh[4];
    if ((t & 63) == 0) sh[t >> 6] = s;
    __syncthreads();
    if (t == 0) bsums[blockIdx.x] = sh[0] + sh[1] + sh[2] + sh[3];
}

// one block, nb <= 256: exclusive offsets of block sums; total -> ofs[N]
__global__ __launch_bounds__(256) void scan_top_k(const int* __restrict__ bsums,
                                                  int* __restrict__ bofs,
                                                  int* __restrict__ ofs, int nb, int N) {
    __shared__ int s[256];
    int t = threadIdx.x;
    int v = (t < nb) ? bsums[t] : 0;
    s[t] = v;
    __syncthreads();
    #pragma unroll
    for (int o = 1; o < 256; o <<= 1) {
        int u = (t >= o) ? s[t - o] : 0;
        __syncthreads();
        s[t] += u;
        __syncthreads();
    }
    if (t < nb) bofs[t] = s[t] - v;  // exclusive
    if (t == 255) ofs[N] = s[255];   // grand total
}

__global__ __launch_bounds__(256) void scan_final_k(const int* __restrict__ deg,
                                                    const int* __restrict__ bofs,
                                                    int* __restrict__ ofs,
                                                    int* __restrict__ cursor, int N) {
    __shared__ int s[256];
    int t = threadIdx.x;
    int base = blockIdx.x * 1024 + t * 4;
    int v0 = 0, v1 = 0, v2 = 0, v3 = 0;
    if (base + 3 < N) {
        int4 v = *(const int4*)(deg + base);
        v0 = v.x; v1 = v.y; v2 = v.z; v3 = v.w;
    } else {
        if (base + 0 < N) v0 = deg[base + 0];
        if (base + 1 < N) v1 = deg[base + 1];
        if (base + 2 < N) v2 = deg[base + 2];
        if (base + 3 < N) v3 = deg[base + 3];
    }
    int tot = v0 + v1 + v2 + v3;
    s[t] = tot;
    __syncthreads();
    #pragma unroll
    for (int o = 1; o < 256; o <<= 1) {
        int u = (t >= o) ? s[t - o] : 0;
        __syncthreads();
        s[t] += u;
        __syncthreads();
    }
    int run = bofs[blockIdx.x] + s[t] - tot;  // exclusive prefix for this thread
    if (base + 0 < N) { ofs[base + 0] = run; cursor[base + 0] = run; run += v0; }
    if (base + 1 < N) { ofs[base + 1] = run; cursor[base + 1] = run; run += v1; }
    if (base + 2 < N) { ofs[base + 2] = run; cursor[base + 2] = run; run += v2; }
    if (base + 3 < N) { ofs[base + 3] = run; cursor[base + 3] = run; }
}

__global__ void scatter_k(const int* __restrict__ src, const int* __restrict__ dst,
                          int* __restrict__ cursor, int* __restrict__ csr, int E, int N) {
    int i = blockIdx.x * blockDim.x + threadIdx.x;
    if (i < E) {
        int d = dst[i];
        int p = atomicAdd(&cursor[d], 1);
        csr[p] = src[i];
    } else if (i < E + N) {
        int n = i - E;
        int p = atomicAdd(&cursor[n], 1);
        csr[p] = n;
    }
}

// ---------------- fp32 tiled GEMM: C = A[M,K] @ B[K,Nn] ----------------
// BM=BN=64, BK=32, block (16,16), 4x4 per thread.
// MODE 0: plain fp32 C.  MODE 1: layer-1 fuse (64ch/head): fp16 h + alpha dots
// via 16-lane shuffle.  MODE 2: layer-2 fuse (16ch/head, Nn=64): fp16 h +
// alpha dots via 4-lane shuffle.

template <int MODE>
__global__ __launch_bounds__(256) void sgemm_k(const float* __restrict__ A,
                                               const float* __restrict__ B,
                                               float* __restrict__ C_,
                                               int M, int Nn, int K,
                                               __half* __restrict__ hout,
                                               const float* __restrict__ avs,
                                               const float* __restrict__ avd,
                                               float* __restrict__ os,
                                               float* __restrict__ od) {
    constexpr int BM = 64, BN = 64, BK = 32;
    __shared__ float As[BK][BM + 4];
    __shared__ float Bs[BK][BN];
    int tx = threadIdx.x, ty = threadIdx.y;
    int tid = ty * 16 + tx;
    int row0 = blockIdx.y * BM;
    int col0 = blockIdx.x * BN;
    float acc[4][4] = {};
    for (int k0 = 0; k0 < K; k0 += BK) {
        constexpr int AF4 = BM * BK / 4;  // 512
        #pragma unroll
        for (int f = tid; f < AF4; f += 256) {
            int r = f / (BK / 4);
            int c4 = f % (BK / 4);
            int gr = row0 + r;
            float4 v = make_float4(0.f, 0.f, 0.f, 0.f);
            if (gr < M) v = *(const float4*)(A + (size_t)gr * K + k0 + c4 * 4);
            As[c4 * 4 + 0][r] = v.x;
            As[c4 * 4 + 1][r] = v.y;
            As[c4 * 4 + 2][r] = v.z;
            As[c4 * 4 + 3][r] = v.w;
        }
        constexpr int BF4 = BK * BN / 4;  // 512
        #pragma unroll
        for (int f = tid; f < BF4; f += 256) {
            int r = f / (BN / 4);
            int c4 = f % (BN / 4);
            *(float4*)(&Bs[r][c4 * 4]) = *(const float4*)(B + (size_t)(k0 + r) * Nn + col0 + c4 * 4);
        }
        __syncthreads();
        #pragma unroll
        for (int k = 0; k < BK; k++) {
            float a4[4], b4[4];
            *(float4*)a4 = *(const float4*)&As[k][ty * 4];
            *(float4*)b4 = *(const float4*)&Bs[k][tx * 4];
            #pragma unroll
            for (int i = 0; i < 4; i++)
                #pragma unroll
                for (int j = 0; j < 4; j++)
                    acc[i][j] = fmaf(a4[i], b4[j], acc[i][j]);
        }
        __syncthreads();
    }
    if (MODE == 0) {
        #pragma unroll
        for (int i = 0; i < 4; i++) {
            int gr = row0 + ty * 4 + i;
            if (gr < M) {
                *(float4*)(C_ + (size_t)gr * Nn + col0 + tx * 4) =
                    make_float4(acc[i][0], acc[i][1], acc[i][2], acc[i][3]);
            }
        }
    } else if (MODE == 1) {
        int h = col0 >> 6;  // head; channel within head = tx*4+j
        float as4[4], ad4[4];
        #pragma unroll
        for (int j = 0; j < 4; j++) {
            as4[j] = avs[h * 64 + tx * 4 + j];
            ad4[j] = avd[h * 64 + tx * 4 + j];
        }
        #pragma unroll
        for (int i = 0; i < 4; i++) {
            int gr = row0 + ty * 4 + i;
            float ps = 0.f, pd = 0.f;
            #pragma unroll
            for (int j = 0; j < 4; j++) {
                ps = fmaf(acc[i][j], as4[j], ps);
                pd = fmaf(acc[i][j], ad4[j], pd);
            }
            #pragma unroll
            for (int o = 8; o >= 1; o >>= 1) {
                ps += __shfl_down(ps, o, 16);
                pd += __shfl_down(pd, o, 16);
            }
            if (gr < M) {
                if (tx == 0) {
                    os[(size_t)gr * HEADS + h] = ps;
                    od[(size_t)gr * HEADS + h] = pd;
                }
                __half2* hp2 = (__half2*)(hout + (size_t)gr * Nn + col0 + tx * 4);
                hp2[0] = __floats2half2_rn(acc[i][0], acc[i][1]);
                hp2[1] = __floats2half2_rn(acc[i][2], acc[i][3]);
            }
        }
    } else {  // MODE 2: Nn == 64, col0 == 0, head = tx>>2, chan-in-head = (tx&3)*4+j
        int h = tx >> 2;
        int cih = (tx & 3) * 4;
        float as4[4], ad4[4];
        #pragma unroll
        for (int j = 0; j < 4; j++) {
            as4[j] = avs[h * 16 + cih + j];
            ad4[j] = avd[h * 16 + cih + j];
        }
        #pragma unroll
        for (int i = 0; i < 4; i++) {
            int gr = row0 + ty * 4 + i;
            float ps = 0.f, pd = 0.f;
            #pragma unroll
            for (int j = 0; j < 4; j++) {
                ps = fmaf(acc[i][j], as4[j], ps);
                pd = fmaf(acc[i][j], ad4[j], pd);
            }
            ps += __shfl_down(ps, 2, 4); ps += __shfl_down(ps, 1, 4);
            pd += __shfl_down(pd, 2, 4); pd += __shfl_down(pd, 1, 4);
            if (gr < M) {
                if ((tx & 3) == 0) {
                    os[(size_t)gr * HEADS + h] = ps;
                    od[(size_t)gr * HEADS + h] = pd;
                }
                __half2* hp2 = (__half2*)(hout + (size_t)gr * 64 + tx * 4);
                hp2[0] = __floats2half2_rn(acc[i][0], acc[i][1]);
                hp2[1] = __floats2half2_rn(acc[i][2], acc[i][3]);
            }
        }
    }
}

// ---------------- GAT aggregation layer 1 (C=64, fp16 gather) ----------------

__global__ __launch_bounds__(256) void gat_agg64_f16_k(
    const __half* __restrict__ hsrc,  // [N, 256] fp16
    const float* __restrict__ as,     // [N, 4]
    const float* __restrict__ ad,     // [N, 4]
    const int* __restrict__ ofs,
    const int* __restrict__ csr,
    const float* __restrict__ bias,   // [256]
    float* __restrict__ out, int N) {
    int node = blockIdx.x * 4 + (threadIdx.x >> 6);
    if (node >= N) return;
    int l = threadIdx.x & 63;
    int h = l >> 4;       // head of my channels AND my alpha subgroup
    int je = l & 15;      // alpha edge slot
    int hb = h << 4;
    int beg = ofs[node], end = ofs[node + 1];
    float adh = ad[(size_t)node * HEADS + h];
    float4 bv = *(const float4*)(bias + l * 4);
    float m = -INFINITY, den = 0.f;
    float4 acc = make_float4(0.f, 0.f, 0.f, 0.f);
    for (int base = beg; base < end; base += 16) {
        int cl = min(16, end - base);
        int s = 0;
        float e = -INFINITY;
        if (je < cl) {
            s = csr[base + je];
            float a = as[(size_t)s * HEADS + h] + adh;
            e = (a > 0.f) ? a : 0.2f * a;
        }
        float cmax = e;
        #pragma unroll
        for (int o = 8; o >= 1; o >>= 1) cmax = fmaxf(cmax, __shfl_xor(cmax, o));
        float m_new = fmaxf(m, cmax);
        float p = (je < cl) ? __expf(e - m_new) : 0.f;
        float sum = p;
        #pragma unroll
        for (int o = 8; o >= 1; o >>= 1) sum += __shfl_xor(sum, o);
        float sc = __expf(m - m_new);  // 0 on first chunk
        den = den * sc + sum;
        m = m_new;
        acc.x *= sc; acc.y *= sc; acc.z *= sc; acc.w *= sc;
        int j = 0;
        for (; j + 4 <= cl; j += 4) {
            float p0 = __shfl(p, hb + j),     p1 = __shfl(p, hb + j + 1);
            float p2 = __shfl(p, hb + j + 2), p3 = __shfl(p, hb + j + 3);
            int s0 = __shfl(s, hb + j),     s1 = __shfl(s, hb + j + 1);
            int s2 = __shfl(s, hb + j + 2), s3 = __shfl(s, hb + j + 3);
            uint2 r0 = *(const uint2*)(hsrc + (size_t)s0 * 256 + l * 4);
            uint2 r1 = *(const uint2*)(hsrc + (size_t)s1 * 256 + l * 4);
            uint2 r2 = *(const uint2*)(hsrc + (size_t)s2 * 256 + l * 4);
            uint2 r3 = *(const uint2*)(hsrc + (size_t)s3 * 256 + l * 4);
            float2 a0 = __half22float2(*(__half2*)&r0.x), b0 = __half22float2(*(__half2*)&r0.y);
            float2 a1 = __half22float2(*(__half2*)&r1.x), b1 = __half22float2(*(__half2*)&r1.y);
            float2 a2 = __half22float2(*(__half2*)&r2.x), b2 = __half22float2(*(__half2*)&r2.y);
            float2 a3 = __half22float2(*(__half2*)&r3.x), b3 = __half22float2(*(__half2*)&r3.y);
            acc.x = fmaf(p0, a0.x, acc.x); acc.y = fmaf(p0, a0.y, acc.y);
            acc.z = fmaf(p0, b0.x, acc.z); acc.w = fmaf(p0, b0.y, acc.w);
            acc.x = fmaf(p1, a1.x, acc.x); acc.y = fmaf(p1, a1.y, acc.y);
            acc.z = fmaf(p1, b1.x, acc.z); acc.w = fmaf(p1, b1.y, acc.w);
            acc.x = fmaf(p2, a2.x, acc.x); acc.y = fmaf(p2, a2.y, acc.y);
            acc.z = fmaf(p2, b2.x, acc.z); acc.w = fmaf(p2, b2.y, acc.w);
            acc.x = fmaf(p3, a3.x, acc.x); acc.y = fmaf(p3, a3.y, acc.y);
            acc.z = fmaf(p3, b3.x, acc.z); acc.w = fmaf(p3, b3.y, acc.w);
        }
        for (; j < cl; j++) {
            float pj = __shfl(p, hb + j);
            int sj = __shfl(s, hb + j);
            uint2 r0 = *(const uint2*)(hsrc + (size_t)sj * 256 + l * 4);
            float2 a0 = __half22float2(*(__half2*)&r0.x), b0 = __half22float2(*(__half2*)&r0.y);
            acc.x = fmaf(pj, a0.x, acc.x); acc.y = fmaf(pj, a0.y, acc.y);
            acc.z = fmaf(pj, b0.x, acc.z); acc.w = fmaf(pj, b0.y, acc.w);
        }
    }
    float inv = 1.f / den;
    float4 r;
    r.x = fmaxf(fmaf(acc.x, inv, bv.x), 0.f);
    r.y = fmaxf(fmaf(acc.y, inv, bv.y), 0.f);
    r.z = fmaxf(fmaf(acc.z, inv, bv.z), 0.f);
    r.w = fmaxf(fmaf(acc.w, inv, bv.w), 0.f);
    *(float4*)(out + (size_t)node * 256 + l * 4) = r;
}

// ---------------- GAT aggregation layer 2 (C=16, fp16 gather) ----------------

__global__ __launch_bounds__(256) void gat_agg16_f16_k(
    const __half* __restrict__ hsrc,  // [N, 64] fp16
    const float* __restrict__ as,
    const float* __restrict__ ad,
    const int* __restrict__ ofs,
    const int* __restrict__ csr,
    const float* __restrict__ bias,   // [64]
    float* __restrict__ out, int N) {
    int node = blockIdx.x * 4 + (threadIdx.x >> 6);
    if (node >= N) return;
    int l = threadIdx.x & 63;
    int ha = l >> 4;      // alpha subgroup head
    int je = l & 15;      // alpha edge slot
    int q = l & 15;       // row position: channels [4q,4q+4)
    int hh = q >> 2;      // head of my channels
    int eg = l >> 4;      // edge subslot
    int beg = ofs[node], end = ofs[node + 1];
    float adh = ad[(size_t)node * HEADS + ha];
    float m = -INFINITY, den = 0.f;
    float4 acc = make_float4(0.f, 0.f, 0.f, 0.f);
    for (int base = beg; base < end; base += 16) {
        int cl = min(16, end - base);
        int s = 0;
        float e = -INFINITY;
        if (je < cl) {
            s = csr[base + je];
            float a = as[(size_t)s * HEADS + ha] + adh;
            e = (a > 0.f) ? a : 0.2f * a;
        }
        float cmax = e;
        #pragma unroll
        for (int o = 8; o >= 1; o >>= 1) cmax = fmaxf(cmax, __shfl_xor(cmax, o));
        float m_new = fmaxf(m, cmax);
        float p = (je < cl) ? __expf(e - m_new) : 0.f;
        float sum = p;
        #pragma unroll
        for (int o = 8; o >= 1; o >>= 1) sum += __shfl_xor(sum, o);
        float sc = __expf(m - m_new);
        den = den * sc + sum;
        m = m_new;
        float sch = __shfl(sc, hh << 4);  // rescale factor of MY channel head
        acc.x *= sch; acc.y *= sch; acc.z *= sch; acc.w *= sch;
        for (int j0 = 0; j0 < cl; j0 += 4) {
            int j = j0 + eg;
            int jc = min(j, cl - 1);
            float pj = __shfl(p, (hh << 4) + jc);
            int sj = __shfl(s, (hh << 4) + jc);
            if (j < cl) {
                uint2 raw = *(const uint2*)(hsrc + (size_t)sj * 64 + q * 4);
                float2 f0 = __half22float2(*(__half2*)&raw.x);
                float2 f1 = __half22float2(*(__half2*)&raw.y);
                acc.x = fmaf(pj, f0.x, acc.x); acc.y = fmaf(pj, f0.y, acc.y);
                acc.z = fmaf(pj, f1.x, acc.z); acc.w = fmaf(pj, f1.y, acc.w);
            }
        }
    }
    acc.x += __shfl_xor(acc.x, 16); acc.y += __shfl_xor(acc.y, 16);
    acc.z += __shfl_xor(acc.z, 16); acc.w += __shfl_xor(acc.w, 16);
    acc.x += __shfl_xor(acc.x, 32); acc.y += __shfl_xor(acc.y, 32);
    acc.z += __shfl_xor(acc.z, 32); acc.w += __shfl_xor(acc.w, 32);
    float denh = __shfl(den, hh << 4);
    if (eg == 0) {
        float inv = 1.f / denh;
        float4 bv = *(const float4*)(bias + q * 4);
        float4 r;
        r.x = fmaxf(fmaf(acc.x, inv, bv.x), 0.f);
        r.y = fmaxf(fmaf(acc.y, inv, bv.y), 0.f);
        r.z = fmaxf(fmaf(acc.z, inv, bv.z), 0.f);
        r.w = fmaxf(fmaf(acc.w, inv, bv.w), 0.f);
        *(float4*)(out + (size_t)node * 64 + q * 4) = r;
    }
}

// ---------------- pooling + FC ----------------

__global__ void graph_bounds_k(const int* __restrict__ batch, int N, int* __restrict__ bstart) {
    int g = threadIdx.x;
    if (g <= 64) {
        int lo = 0, hi = N;
        while (lo < hi) {
            int mid = (lo + hi) >> 1;
            if (batch[mid] < g) lo = mid + 1; else hi = mid;
        }
        bstart[g] = lo;
    }
}

__global__ void pool_zero_k(float* __restrict__ sums) {
    sums[blockIdx.x * blockDim.x + threadIdx.x] = 0.f;
}

__global__ __launch_bounds__(256) void pool_sum_k(const float* __restrict__ g2,
                                                  const int* __restrict__ batch,
                                                  float* __restrict__ sums, int N) {
    int c = threadIdx.x & 63;
    int r = threadIdx.x >> 6;
    int base = blockIdx.x * 256;
    int lim = min(base + 256, N);
    float acc = 0.f;
    int cur = -1;
    for (int n = base + r; n < lim; n += 4) {
        int g = batch[n];
        if (g != cur) {
            if (cur >= 0) atomicAdd(&sums[cur * 64 + c], acc);
            acc = 0.f;
            cur = g;
        }
        acc += g2[(size_t)n * 64 + c];
    }
    if (cur >= 0) atomicAdd(&sums[cur * 64 + c], acc);
}

__global__ void fc_k(const float* __restrict__ sums, const int* __restrict__ bstart,
                     const float* __restrict__ w, const float* __restrict__ b,
                     float* __restrict__ out) {
    int g = blockIdx.x, o = threadIdx.x;  // 32 threads
    float cnt = (float)max(bstart[g + 1] - bstart[g], 1);
    float inv = 1.f / cnt;
    float acc = b[o];
    for (int k = 0; k < 64; k++) acc = fmaf(sums[g * 64 + k] * inv, w[k * 32 + o], acc);
    out[g * 32 + o] = acc;
}

// ---------------- launch ----------------

static inline size_t align_up(size_t x, size_t a) { return (x + a - 1) & ~(a - 1); }

extern "C" void kernel_launch(void* const* d_in, const int* in_sizes, int n_in,
                              void* d_out, int out_size, void* d_ws, size_t ws_size,
                              hipStream_t stream) {
    const float* x      = (const float*)d_in[0];
    const int*   ei     = (const int*)d_in[1];
    const int*   batch  = (const int*)d_in[2];
    const float* W1     = (const float*)d_in[3];
    const float* a_src1 = (const float*)d_in[4];
    const float* a_dst1 = (const float*)d_in[5];
    const float* b1     = (const float*)d_in[6];
    const float* W2     = (const float*)d_in[7];
    const float* a_src2 = (const float*)d_in[8];
    const float* a_dst2 = (const float*)d_in[9];
    const float* b2     = (const float*)d_in[10];
    const float* fc_w   = (const float*)d_in[11];
    const float* fc_b   = (const float*)d_in[12];
    float* out = (float*)d_out;

    const int N = in_sizes[2];
    const int E = in_sizes[1] / 2;
    const int F_in = in_sizes[0] / N;   // 128
    const int D1 = HEADS * 64;          // 256
    const int D2 = HEADS * 16;          // 64

    const int* src = ei;
    const int* dst = ei + E;

    char* w = (char*)d_ws;
    size_t off = 0;
    auto alloc = [&](size_t bytes) {
        size_t p = off;
        off = align_up(off + bytes, 256);
        return (void*)(w + p);
    };
    int* deg    = (int*)alloc((size_t)N * 4);
    int* ofs    = (int*)alloc((size_t)(N + 1) * 4);
    int* cursor = (int*)alloc((size_t)N * 4);
    int* csr    = (int*)alloc((size_t)(E + N) * 4);
    int* bsums  = (int*)alloc(256 * 4);
    int* bofs   = (int*)alloc(256 * 4);
    int* bstart = (int*)alloc(65 * 4);
    float* pooled = (float*)alloc(64 * 64 * 4);
    float* as1  = (float*)alloc((size_t)N * HEADS * 4);
    float* ad1  = (float*)alloc((size_t)N * HEADS * 4);
    float* as2  = (float*)alloc((size_t)N * HEADS * 4);
    float* ad2  = (float*)alloc((size_t)N * HEADS * 4);
    float* g1   = (float*)alloc((size_t)N * D1 * 4);
    __half* h1h = (__half*)alloc((size_t)N * D1 * 2);   // fp16 layer-1 features
    __half* h2h = (__half*)alloc((size_t)N * D2 * 2);   // fp16 layer-2 features
    float* g2   = (float*)alloc((size_t)N * D2 * 4);

    const int nb = (N + 1023) / 1024;   // scan blocks (<=256 for N<=262144)

    // --- CSR build ---
    init_deg_k<<<(N + 255) / 256, 256, 0, stream>>>(deg, N);
    count_deg_k<<<(E + 255) / 256, 256, 0, stream>>>(dst, deg, E);
    scan_part_k<<<nb, 256, 0, stream>>>(deg, bsums, N);
    scan_top_k<<<1, 256, 0, stream>>>(bsums, bofs, ofs, nb, N);
    scan_final_k<<<nb, 256, 0, stream>>>(deg, bofs, ofs, cursor, N);
    scatter_k<<<(E + N + 255) / 256, 256, 0, stream>>>(src, dst, cursor, csr, E, N);

    // --- layer 1: GEMM + fused fp16 store + fused alpha dots ---
    {
        dim3 grid(D1 / 64, (N + 63) / 64);
        sgemm_k<1><<<grid, dim3(16, 16), 0, stream>>>(
            x, W1, nullptr, N, D1, F_in, h1h, a_src1, a_dst1, as1, ad1);
    }
    gat_agg64_f16_k<<<(N + 3) / 4, 256, 0, stream>>>(h1h, as1, ad1, ofs, csr, b1, g1, N);

    // --- layer 2: GEMM + fused fp16 store + fused alpha dots ---
    {
        dim3 grid(D2 / 64, (N + 63) / 64);
        sgemm_k<2><<<grid, dim3(16, 16), 0, stream>>>(
            g1, W2, nullptr, N, D2, D1, h2h, a_src2, a_dst2, as2, ad2);
    }
    gat_agg16_f16_k<<<(N + 3) / 4, 256, 0, stream>>>(h2h, as2, ad2, ofs, csr, b2, g2, N);

    // --- pool + fc ---
    graph_bounds_k<<<1, 128, 0, stream>>>(batch, N, bstart);
    pool_zero_k<<<16, 256, 0, stream>>>(pooled);
    pool_sum_k<<<(N + 255) / 256, 256, 0, stream>>>(g2, batch, pooled, N);
    fc_k<<<64, 32, 0, stream>>>(pooled, bstart, fc_w, fc_b, out);
}